// Round 5
// baseline (8749.470 us; speedup 1.0000x reference)
//
#include <hip/hip_runtime.h>

// ---------------------------------------------------------------------------
// Persistent weight-stationary LSTM, bf16 MFMA, decoupled per-layer sync.
// T=1024 B=64 C=256 H=512, 2 layers, fp32 in/out.
//  - 256 blocks x 256 threads, 1 block/CU; blocks 0..127 = layer0,
//    128..255 = layer1. NO full-grid barrier: each layer is its own group.
//  - h0 is a 4-slot ring: layer0 step j writes slot (j+1)&3, layer1 step i
//    reads slot (i+1)&3. Layer0 runs up to 3 steps ahead; cross-layer waits
//    (gen0 >= i+1 for layer1, gen1 >= j-3 for layer0) are satisfied ahead of
//    time in steady state -> period = layer1's own loop, skew absorbed.
//  - Per-WAVE completion flags (1024 slots, 64B apart); no __syncthreads in
//    the tick loop. Group aggregator (block 0 / 128) scans its 512 wave-slots
//    (8/lane), publishes genL to 8 spread lines; workers poll 2 gen lines.
//    Poll traffic ~2K loads/round (R3's 65K/round melted the LLC).
//  - Cross-block data via sc0/sc1 (LLC-coherent) ops; no fences anywhere.
//    Producer order: h-store -> vmcnt(0) -> wave flag store.
//  - h-fragment loads: inline-asm global_load_dwordx4 sc0 sc1, all in flight
//    in one LLC round; layer1 overlaps h1-MFMAs with h0-load flight.
//  - mfma_f32_16x16x32_bf16: A[m=lane&15][k=quad*8+j], B(N,K)[n=lane&15][k=quad*8+j],
//    D[m=quad*4+reg][n=lane&15]  (guide-verified mapping, m90/m97 convention)
// ---------------------------------------------------------------------------

#define TT 1024
#define BB 64
#define CC 256
#define HH 512
#define Y_ELEMS (TT * BB * HH)
#define S_ELEMS (BB * HH)

typedef __attribute__((ext_vector_type(8))) short bf16x8;
typedef __attribute__((ext_vector_type(4))) float f32x4;
typedef unsigned int u32;
typedef unsigned short u16;
typedef unsigned long long u64;

// ---- ws layout (bytes) ----
#define WS_BAR 0           // 1024 wave-slots * 64B
#define WS_GEN 65536       // 16 gen lines * 128B (gen0: 0..7, gen1: 8..15)
#define WS_BSUM0 69632     // 2048 f32
#define WS_BSUM1 77824     // 2048 f32
#define WS_H0 86016        // 4 * 65536 (h0 ring, bf16)
#define WS_H1 348160       // 2 * 65536 (h1 ping-pong, bf16)
#define WS_WPK0 479232     // 128*24*64*8 bf16
#define WS_WPK1 3624960    // 128*32*64*8 bf16
// end 7819264 (~7.82 MB)

__device__ __forceinline__ u16 f2b_rne(float f) {
    u32 u = __float_as_uint(f);
    return (u16)((u + 0x7FFFu + ((u >> 16) & 1u)) >> 16);
}
__device__ __forceinline__ u16 f2b_fast(float f) {  // round-half-up, 2 ops
    return (u16)((__float_as_uint(f) + 0x8000u) >> 16);
}
__device__ __forceinline__ float sigf(float z) { return 1.0f / (1.0f + __expf(-z)); }
__device__ __forceinline__ float tanh_f(float z) { return 2.0f / (1.0f + __expf(-2.0f * z)) - 1.0f; }

__device__ __forceinline__ bf16x8 pack8(float4 a, float4 b) {
    union { u16 u[8]; bf16x8 v; } r;
    r.u[0] = f2b_fast(a.x); r.u[1] = f2b_fast(a.y); r.u[2] = f2b_fast(a.z); r.u[3] = f2b_fast(a.w);
    r.u[4] = f2b_fast(b.x); r.u[5] = f2b_fast(b.y); r.u[6] = f2b_fast(b.z); r.u[7] = f2b_fast(b.w);
    return r.v;
}

__device__ __forceinline__ u32 ld_u32_sc(const u32* p) {
    return __hip_atomic_load(p, __ATOMIC_RELAXED, __HIP_MEMORY_SCOPE_AGENT);
}
__device__ __forceinline__ void st_u32_sc(u32* p, u32 v) {
    __hip_atomic_store(p, v, __ATOMIC_RELAXED, __HIP_MEMORY_SCOPE_AGENT);
}
__device__ __forceinline__ void st_h_sc(u16* p, u16 v) {
    __hip_atomic_store(p, v, __ATOMIC_RELAXED, __HIP_MEMORY_SCOPE_AGENT);
}

// N cache-bypassing 16B loads, base + compile-time offsets, issued
// back-to-back with forced-live destinations -> one LLC latency round.
template <int I, int N>
struct FragLd {
    static __device__ __forceinline__ void go(f32x4* d, const u16* p) {
        asm volatile("global_load_dwordx4 %0, %1, off offset:%c2 sc0 sc1"
                     : "=&v"(d[I]) : "v"(p), "n"(I * 64) : "memory");
        FragLd<I + 1, N>::go(d, p);
    }
};
template <int N>
struct FragLd<N, N> {
    static __device__ __forceinline__ void go(f32x4*, const u16*) {}
};

// ---- init: zero flag region, bsum = bih+bhh, h buffers <- bf16(initial h) ----
__global__ void k_init(const float* __restrict__ bih0, const float* __restrict__ bhh0,
                       const float* __restrict__ bih1, const float* __restrict__ bhh1,
                       const float* __restrict__ h00, const float* __restrict__ h01,
                       unsigned char* __restrict__ ws) {
    u32* bar = (u32*)(ws + WS_BAR);
    float* bs0 = (float*)(ws + WS_BSUM0);
    float* bs1 = (float*)(ws + WS_BSUM1);
    u16* h0 = (u16*)(ws + WS_H0);   // ring slot 0
    u16* h1 = (u16*)(ws + WS_H1);   // pp buffer 0
    int t = blockIdx.x * 256 + threadIdx.x;  // 32768 threads
    if (t < 16896) bar[t] = 0u;              // wave-slots + gen lines
    if (t < 2048) { bs0[t] = bih0[t] + bhh0[t]; bs1[t] = bih1[t] + bhh1[t]; }
    if (t < S_ELEMS) { h0[t] = f2b_rne(h00[t]); h1[t] = f2b_rne(h01[t]); }
}

// ---- weight pack: fp32 [4H,K] -> bf16 B-frag order wpk[bidL][kt][lane][8] ----
// rows permuted: n-index (lane&15) = gg*4+jj  <->  W row = gg*512 + bidL*4 + jj
__global__ void k_wprep(const float* __restrict__ Wih0, const float* __restrict__ Whh0,
                        const float* __restrict__ Wih1, const float* __restrict__ Whh1,
                        unsigned char* __restrict__ ws) {
    u16* wpk0 = (u16*)(ws + WS_WPK0);
    u16* wpk1 = (u16*)(ws + WS_WPK1);
    int u = blockIdx.x * 256 + threadIdx.x;  // 458752 threads
    const float* s;
    u16* d;
    if (u < 128 * 24 * 64) {  // layer0: 8 x-tiles (K=256) + 16 h-tiles (K=512)
        int bidL = u / (24 * 64);
        int kt = (u >> 6) % 24;
        int lane = u & 63;
        int n = lane & 15, quad = lane >> 4;
        int row = (n >> 2) * 512 + bidL * 4 + (n & 3);
        int k = kt * 32 + quad * 8;
        s = (k < 256) ? (Wih0 + (size_t)row * 256 + k) : (Whh0 + (size_t)row * 512 + (k - 256));
        d = wpk0 + (size_t)((bidL * 24 + kt) * 64 + lane) * 8;
    } else {  // layer1: 16 y0-tiles + 16 h1-tiles (K=1024)
        int v = u - 128 * 24 * 64;
        int bidL = v / (32 * 64);
        int kt = (v >> 6) % 32;
        int lane = v & 63;
        int n = lane & 15, quad = lane >> 4;
        int row = (n >> 2) * 512 + bidL * 4 + (n & 3);
        int k = kt * 32 + quad * 8;
        s = (k < 512) ? (Wih1 + (size_t)row * 512 + k) : (Whh1 + (size_t)row * 512 + (k - 512));
        d = wpk1 + (size_t)((bidL * 32 + kt) * 64 + lane) * 8;
    }
    #pragma unroll
    for (int i = 0; i < 8; ++i) d[i] = f2b_rne(s[i]);
}

// ---- the persistent tick loop, templated on layer ----
template <int LAYER>
__device__ void run_ticks(const float* __restrict__ x, const float* __restrict__ c0,
                          float* __restrict__ out, unsigned char* __restrict__ ws, int bidL) {
    constexpr int NKT = (LAYER == 0) ? 24 : 32;
    u32* slots = (u32*)(ws + WS_BAR);              // wave-slot stride: 16 u32 (64B)
    u32* gen0 = (u32*)(ws + WS_GEN);               // 8 lines, stride 32 u32
    u32* gen1 = gen0 + 8 * 32;
    const float* bs = (const float*)(ws + (LAYER == 0 ? WS_BSUM0 : WS_BSUM1));
    u16* h0r[4] = { (u16*)(ws + WS_H0),              (u16*)(ws + WS_H0) + S_ELEMS,
                    (u16*)(ws + WS_H0) + 2 * S_ELEMS, (u16*)(ws + WS_H0) + 3 * S_ELEMS };
    u16* h1p[2] = { (u16*)(ws + WS_H1), (u16*)(ws + WS_H1) + S_ELEMS };
    const u16* wpk = (const u16*)(ws + (LAYER == 0 ? WS_WPK0 : WS_WPK1));

    const int tid = threadIdx.x, lane = tid & 63, wave = tid >> 6;
    const int r16 = lane & 15, quad = lane >> 4, q8 = quad * 8;
    const int gg = r16 >> 2, jj = r16 & 3;
    const int b0 = wave * 16;
    const int col = bidL * 4 + jj;            // h column this lane finalizes
    const int myb = b0 + quad * 4 + gg;       // batch this lane finalizes
    const int sl0 = (quad << 4) | (0 << 2) | jj;
    const int sl1 = (quad << 4) | (1 << 2) | jj;
    const int sl2 = (quad << 4) | (2 << 2) | jj;
    const int sl3 = (quad << 4) | (3 << 2) | jj;

    const int wid = blockIdx.x * 4 + wave;    // global wave id (0..1023)
    u32* myflag = slots + (u32)wid * 16;
    const bool AGG = (bidL == 0);             // block 0 / block 128 aggregate
    // aggregator: 8 own-group wave-slots per lane
    const u32* ag[8];
    if (AGG) {
        const int obase = (LAYER == 0) ? 0 : 512;
        #pragma unroll
        for (int k = 0; k < 8; ++k) ag[k] = slots + (u32)(obase + lane * 8 + k) * 16;
    }
    u32* gpub = (LAYER == 0) ? gen0 : gen1;                    // own gen (agg publishes)
    const u32* gownp = ((LAYER == 0) ? gen0 : gen1) + ((u32)blockIdx.x & 7) * 32;
    const u32* gothp = ((LAYER == 0) ? gen1 : gen0) + ((u32)blockIdx.x & 7) * 32;

    // biases (hoisted), c state in register for the whole run
    const float bi = bs[0 * HH + col], bf_ = bs[1 * HH + col];
    const float bg = bs[2 * HH + col], bo = bs[3 * HH + col];
    float c = c0[myb * HH + col];

    // weight fragments (reloads, if any, hit L1/L2 — nothing invalidates)
    f32x4 wf[NKT];
    {
        const u16* wp = wpk + (size_t)(bidL * NKT * 64 + lane) * 8;
        #pragma unroll
        for (int kt = 0; kt < NKT; ++kt) wf[kt] = *(const f32x4*)(wp + (size_t)kt * 64 * 8);
        #pragma unroll
        for (int kt = 0; kt < NKT; ++kt) asm volatile("" : "+v"(wf[kt]));
    }

    // layer0: x prefetch registers (step 0 issued before the loop)
    float4 xf0[8], xf1[8];
    if (LAYER == 0) {
        const float* xp = x + (size_t)(b0 + r16) * CC + q8;
        #pragma unroll
        for (int kt = 0; kt < 8; ++kt) {
            xf0[kt] = *(const float4*)(xp + kt * 32);
            xf1[kt] = *(const float4*)(xp + kt * 32 + 4);
        }
    }

    for (int s = 0; s < TT; ++s) {
        // ---- WAIT: own group done step s-1; cross-layer ring constraints ----
        const u32 no = (u32)s;
        const u32 nx = (LAYER == 0) ? (u32)((s >= 4) ? (s - 3) : 0) : (u32)(s + 1);
        if (AGG) {
            // every wave scans; exits on its own observation (no syncthreads)
            while (true) {
                u32 v0 = ld_u32_sc(ag[0]), v1 = ld_u32_sc(ag[1]);
                u32 v2 = ld_u32_sc(ag[2]), v3 = ld_u32_sc(ag[3]);
                u32 v4 = ld_u32_sc(ag[4]), v5 = ld_u32_sc(ag[5]);
                u32 v6 = ld_u32_sc(ag[6]), v7 = ld_u32_sc(ag[7]);
                u32 go = ld_u32_sc(gothp);
                u32 m = min(min(min(v0, v1), min(v2, v3)), min(min(v4, v5), min(v6, v7)));
                if (__all((int)(m >= no && go >= nx))) break;
            }
            if (tid == 0 && s > 0) {
                #pragma unroll
                for (int k = 0; k < 8; ++k) st_u32_sc(gpub + k * 32, no);
            }
        } else {
            u32 a, b2;
            do {
                a = ld_u32_sc(gownp);
                b2 = ld_u32_sc(gothp);
            } while (a < no || b2 < nx);
        }

        // ---- LOAD + MFMA ----
        f32x4 a0 = {0.f,0.f,0.f,0.f}, a1 = {0.f,0.f,0.f,0.f};
        f32x4 a2 = {0.f,0.f,0.f,0.f}, a3 = {0.f,0.f,0.f,0.f};
        if (LAYER == 0) {
            f32x4 afr[16];
            const u16* hp = h0r[s & 3] + (size_t)(b0 + r16) * HH + q8;
            FragLd<0, 16>::go(afr, hp);
            #pragma unroll
            for (int kt = 0; kt < 8; ++kt) {      // x proj overlaps h-load flight
                bf16x8 a = pack8(xf0[kt], xf1[kt]);
                bf16x8 wv = __builtin_bit_cast(bf16x8, wf[kt]);
                f32x4& dst = (kt & 2) ? ((kt & 1) ? a3 : a2) : ((kt & 1) ? a1 : a0);
                dst = __builtin_amdgcn_mfma_f32_16x16x32_bf16(a, wv, dst, 0, 0, 0);
            }
            asm volatile("s_waitcnt vmcnt(0)" ::: "memory");
            __builtin_amdgcn_sched_barrier(0);
            #pragma unroll
            for (int kt = 0; kt < 16; ++kt) {
                bf16x8 av = __builtin_bit_cast(bf16x8, afr[kt]);
                bf16x8 wv = __builtin_bit_cast(bf16x8, wf[8 + kt]);
                f32x4& dst = (kt & 2) ? ((kt & 1) ? a3 : a2) : ((kt & 1) ? a1 : a0);
                dst = __builtin_amdgcn_mfma_f32_16x16x32_bf16(av, wv, dst, 0, 0, 0);
            }
        } else {
            f32x4 afr[32];
            const u16* pa = h0r[(s + 1) & 3] + (size_t)(b0 + r16) * HH + q8;  // y0[s]
            const u16* pb = h1p[s & 1] + (size_t)(b0 + r16) * HH + q8;        // h1[s-1]
            FragLd<0, 16>::go(afr + 16, pb);   // h1 first
            FragLd<0, 16>::go(afr, pa);        // h0 second
            asm volatile("s_waitcnt vmcnt(16)" ::: "memory");  // h1 ready
            __builtin_amdgcn_sched_barrier(0);
            #pragma unroll
            for (int kt = 16; kt < 32; ++kt) {  // h1-MFMAs overlap h0-load flight
                bf16x8 av = __builtin_bit_cast(bf16x8, afr[kt]);
                bf16x8 wv = __builtin_bit_cast(bf16x8, wf[kt]);
                f32x4& dst = (kt & 2) ? ((kt & 1) ? a3 : a2) : ((kt & 1) ? a1 : a0);
                dst = __builtin_amdgcn_mfma_f32_16x16x32_bf16(av, wv, dst, 0, 0, 0);
            }
            asm volatile("s_waitcnt vmcnt(0)" ::: "memory");
            __builtin_amdgcn_sched_barrier(0);
            #pragma unroll
            for (int kt = 0; kt < 16; ++kt) {
                bf16x8 av = __builtin_bit_cast(bf16x8, afr[kt]);
                bf16x8 wv = __builtin_bit_cast(bf16x8, wf[kt]);
                f32x4& dst = (kt & 2) ? ((kt & 1) ? a3 : a2) : ((kt & 1) ? a1 : a0);
                dst = __builtin_amdgcn_mfma_f32_16x16x32_bf16(av, wv, dst, 0, 0, 0);
            }
        }
        f32x4 acc = (a0 + a1) + (a2 + a3);

        // ---- gates for (myb, col): lanes sharing (quad,jj), gg = gate ----
        float gi = 0.f, gf = 0.f, gc = 0.f, go = 0.f;
        #pragma unroll
        for (int r = 0; r < 4; ++r) {
            float v0 = __shfl(acc[r], sl0, 64);
            float v1 = __shfl(acc[r], sl1, 64);
            float v2 = __shfl(acc[r], sl2, 64);
            float v3 = __shfl(acc[r], sl3, 64);
            if (r == gg) { gi = v0; gf = v1; gc = v2; go = v3; }
        }
        gi = sigf(gi + bi);
        gf = sigf(gf + bf_);
        gc = tanh_f(gc + bg);
        go = sigf(go + bo);
        c = gf * c + gi * gc;
        const float h = go * tanh_f(c);

        u16* hw = (LAYER == 0) ? h0r[(s + 1) & 3] : h1p[(s + 1) & 1];
        st_h_sc(&hw[myb * HH + col], f2b_rne(h));

        // ---- per-wave arrival: drain h store, flag (no syncthreads) ----
        asm volatile("s_waitcnt vmcnt(0)" ::: "memory");
        if (lane == 0) st_u32_sc(myflag, (u32)(s + 1));

        // ---- shadow work (flies while peers finish / flags propagate) ----
        if (LAYER == 1) {
            out[(size_t)s * S_ELEMS + myb * HH + col] = h;
            if (s == TT - 1) {
                float* fin = out + Y_ELEMS + 2 * S_ELEMS;
                fin[myb * HH + col] = h;
                fin[S_ELEMS + myb * HH + col] = c;
            }
        } else {
            if (s == TT - 1) {
                float* fin = out + Y_ELEMS;
                fin[myb * HH + col] = h;
                fin[S_ELEMS + myb * HH + col] = c;
            }
            if (s + 1 < TT) {   // prefetch x[s+1] into registers
                const float* xp = x + ((size_t)(s + 1) * BB + b0 + r16) * CC + q8;
                #pragma unroll
                for (int kt = 0; kt < 8; ++kt) {
                    xf0[kt] = *(const float4*)(xp + kt * 32);
                    xf1[kt] = *(const float4*)(xp + kt * 32 + 4);
                }
            }
        }
    }

    // layer1 step 1023 needs gen0 >= 1024: block 0 publishes it post-loop
    if (LAYER == 0 && AGG && wave == 0) {
        while (true) {
            u32 v0 = ld_u32_sc(ag[0]), v1 = ld_u32_sc(ag[1]);
            u32 v2 = ld_u32_sc(ag[2]), v3 = ld_u32_sc(ag[3]);
            u32 v4 = ld_u32_sc(ag[4]), v5 = ld_u32_sc(ag[5]);
            u32 v6 = ld_u32_sc(ag[6]), v7 = ld_u32_sc(ag[7]);
            u32 m = min(min(min(v0, v1), min(v2, v3)), min(min(v4, v5), min(v6, v7)));
            if (__all((int)(m >= (u32)TT))) break;
        }
        if (lane == 0) {
            #pragma unroll
            for (int k = 0; k < 8; ++k) st_u32_sc(gen0 + k * 32, (u32)TT);
        }
    }
}

__global__ __launch_bounds__(256) __attribute__((amdgpu_waves_per_eu(1, 1)))
void k_lstm(const float* __restrict__ x,
            const float* __restrict__ c00,
            const float* __restrict__ c01,
            float* __restrict__ out,
            unsigned char* __restrict__ ws) {
    const int bid = blockIdx.x;
    if (bid < 128) run_ticks<0>(x, c00, out, ws, bid);
    else           run_ticks<1>(x, c01, out, ws, bid - 128);
}

extern "C" void kernel_launch(void* const* d_in, const int* in_sizes, int n_in,
                              void* d_out, int out_size, void* d_ws, size_t ws_size,
                              hipStream_t stream) {
    const float* x    = (const float*)d_in[0];
    const float* h0_0 = (const float*)d_in[1];
    const float* c0_0 = (const float*)d_in[2];
    const float* h0_1 = (const float*)d_in[3];
    const float* c0_1 = (const float*)d_in[4];
    const float* Wih0 = (const float*)d_in[5];
    const float* Whh0 = (const float*)d_in[6];
    const float* bih0 = (const float*)d_in[7];
    const float* bhh0 = (const float*)d_in[8];
    const float* Wih1 = (const float*)d_in[9];
    const float* Whh1 = (const float*)d_in[10];
    const float* bih1 = (const float*)d_in[11];
    const float* bhh1 = (const float*)d_in[12];
    float* out = (float*)d_out;
    unsigned char* ws = (unsigned char*)d_ws;

    k_init<<<128, 256, 0, stream>>>(bih0, bhh0, bih1, bhh1, h0_0, h0_1, ws);
    k_wprep<<<1792, 256, 0, stream>>>(Wih0, Whh0, Wih1, Whh1, ws);
    k_lstm<<<256, 256, 0, stream>>>(x, c0_0, c0_1, out, ws);
}

// Round 6
// 6412.571 us; speedup vs baseline: 1.3644x; 1.3644x over previous
//
#include <hip/hip_runtime.h>

// ---------------------------------------------------------------------------
// Persistent weight-stationary LSTM, bf16 MFMA, R4 sync + L2-broadcast h.
// T=1024 B=64 C=256 H=512, 2 layers, fp32 in/out.
//  - 256 blocks x 256 threads, 1 block/CU; blocks 0..127 = layer0 (step t),
//    128..255 = layer1 (step t-1); one full-grid flag barrier per tick
//    (R4 structure: block flags -> block0 wave-scan -> gen -> tid0 poll).
//  - KEY CHANGE vs R4: h state kept as FULL HISTORY (1025 slots/layer) when
//    ws_size permits. Fresh addresses every tick => consumer h loads can be
//    CACHED (no sc bits): first toucher per XCD fills L2, other 31 blocks hit
//    L2. LLC read traffic drops 24 MB/tick -> ~1 MB/tick (the R4 bottleneck:
//    column-partitioned blocks each read the full 64/128 KB slab via sc0sc1,
//    128x read amplification, LLC-BW-bound).
//  - Producers still store h with sc0/sc1 (write-through to LLC) and drain
//    vmcnt(0) before flagging -> consumers' L2 misses always see fresh data.
//  - If ws_size < ~142 MB: fall back to exact R4 behavior (2-slot ring,
//    bypass loads) -- never regress.
//  - mfma_f32_16x16x32_bf16: A[m=lane&15][k=quad*8+j], B(N,K)[n=lane&15][k=quad*8+j],
//    D[m=quad*4+reg][n=lane&15]  (guide-verified mapping, m90/m97 convention)
// ---------------------------------------------------------------------------

#define TT 1024
#define BB 64
#define CC 256
#define HH 512
#define Y_ELEMS (TT * BB * HH)
#define S_ELEMS (BB * HH)

typedef __attribute__((ext_vector_type(8))) short bf16x8;
typedef __attribute__((ext_vector_type(4))) float f32x4;
typedef unsigned int u32;
typedef unsigned short u16;
typedef unsigned long long u64;

// ---- ws layout (bytes) ----
#define WS_BAR 0                       // 256 slots * 128B
#define WS_GEN 32768                   // 4 gen lines * 128B
#define WS_BSUM0 36864                 // 2048 f32
#define WS_BSUM1 45056                 // 2048 f32
#define WS_WPK0 53248                  // 128*24*64*8 bf16 (3,145,728 B)
#define WS_WPK1 3198976                // 128*32*64*8 bf16 (4,194,304 B)
#define WS_H0   7393280                // h0 slots (65536 B each)
#define H_SLOT_BYTES 65536
// history mode: 1025 slots/layer -> end = 7393280 + 2*1025*65536 = 141,742,080

__device__ __forceinline__ u16 f2b_rne(float f) {
    u32 u = __float_as_uint(f);
    return (u16)((u + 0x7FFFu + ((u >> 16) & 1u)) >> 16);
}
__device__ __forceinline__ u16 f2b_fast(float f) {  // round-half-up, 2 ops
    return (u16)((__float_as_uint(f) + 0x8000u) >> 16);
}
__device__ __forceinline__ float sigf(float z) { return 1.0f / (1.0f + __expf(-z)); }
__device__ __forceinline__ float tanh_f(float z) { return 2.0f / (1.0f + __expf(-2.0f * z)) - 1.0f; }

__device__ __forceinline__ bf16x8 pack8(float4 a, float4 b) {
    union { u16 u[8]; bf16x8 v; } r;
    r.u[0] = f2b_fast(a.x); r.u[1] = f2b_fast(a.y); r.u[2] = f2b_fast(a.z); r.u[3] = f2b_fast(a.w);
    r.u[4] = f2b_fast(b.x); r.u[5] = f2b_fast(b.y); r.u[6] = f2b_fast(b.z); r.u[7] = f2b_fast(b.w);
    return r.v;
}

__device__ __forceinline__ u32 ld_u32_sc(const u32* p) {
    return __hip_atomic_load(p, __ATOMIC_RELAXED, __HIP_MEMORY_SCOPE_AGENT);
}
__device__ __forceinline__ void st_u32_sc(u32* p, u32 v) {
    __hip_atomic_store(p, v, __ATOMIC_RELAXED, __HIP_MEMORY_SCOPE_AGENT);
}
__device__ __forceinline__ void st_h_sc(u16* p, u16 v) {
    __hip_atomic_store(p, v, __ATOMIC_RELAXED, __HIP_MEMORY_SCOPE_AGENT);
}

// N 16B loads, base + compile-time offsets, back-to-back with forced-live
// destinations -> one latency round. SC=true bypasses L1/L2 (LLC-coherent);
// SC=false is cacheable (history mode: addresses are virgin -> always fresh).
template <int I, int N, bool SC>
struct FragLd {
    static __device__ __forceinline__ void go(f32x4* d, const u16* p) {
        if constexpr (SC)
            asm volatile("global_load_dwordx4 %0, %1, off offset:%c2 sc0 sc1"
                         : "=&v"(d[I]) : "v"(p), "n"(I * 64) : "memory");
        else
            asm volatile("global_load_dwordx4 %0, %1, off offset:%c2"
                         : "=&v"(d[I]) : "v"(p), "n"(I * 64) : "memory");
        FragLd<I + 1, N, SC>::go(d, p);
    }
};
template <int N, bool SC>
struct FragLd<N, N, SC> {
    static __device__ __forceinline__ void go(f32x4*, const u16*) {}
};

// ---- init: zero flags, bsum = bih+bhh, h slot0 <- bf16(initial h) ----
__global__ void k_init(const float* __restrict__ bih0, const float* __restrict__ bhh0,
                       const float* __restrict__ bih1, const float* __restrict__ bhh1,
                       const float* __restrict__ h00, const float* __restrict__ h01,
                       unsigned char* __restrict__ ws, u64 h1off) {
    u32* bar = (u32*)(ws + WS_BAR);
    float* bs0 = (float*)(ws + WS_BSUM0);
    float* bs1 = (float*)(ws + WS_BSUM1);
    u16* h0 = (u16*)(ws + WS_H0);
    u16* h1 = (u16*)(ws + h1off);
    int t = blockIdx.x * 256 + threadIdx.x;  // 32768 threads
    if (t < 8320) bar[t] = 0u;               // slots + gen lines
    if (t < 2048) { bs0[t] = bih0[t] + bhh0[t]; bs1[t] = bih1[t] + bhh1[t]; }
    if (t < S_ELEMS) { h0[t] = f2b_rne(h00[t]); h1[t] = f2b_rne(h01[t]); }
}

// ---- weight pack: fp32 [4H,K] -> bf16 B-frag order wpk[bidL][kt][lane][8] ----
// rows permuted: n-index (lane&15) = gg*4+jj  <->  W row = gg*512 + bidL*4 + jj
__global__ void k_wprep(const float* __restrict__ Wih0, const float* __restrict__ Whh0,
                        const float* __restrict__ Wih1, const float* __restrict__ Whh1,
                        unsigned char* __restrict__ ws) {
    u16* wpk0 = (u16*)(ws + WS_WPK0);
    u16* wpk1 = (u16*)(ws + WS_WPK1);
    int u = blockIdx.x * 256 + threadIdx.x;  // 458752 threads
    const float* s;
    u16* d;
    if (u < 128 * 24 * 64) {  // layer0: 8 x-tiles (K=256) + 16 h-tiles (K=512)
        int bidL = u / (24 * 64);
        int kt = (u >> 6) % 24;
        int lane = u & 63;
        int n = lane & 15, quad = lane >> 4;
        int row = (n >> 2) * 512 + bidL * 4 + (n & 3);
        int k = kt * 32 + quad * 8;
        s = (k < 256) ? (Wih0 + (size_t)row * 256 + k) : (Whh0 + (size_t)row * 512 + (k - 256));
        d = wpk0 + (size_t)((bidL * 24 + kt) * 64 + lane) * 8;
    } else {  // layer1: 16 y0-tiles + 16 h1-tiles (K=1024)
        int v = u - 128 * 24 * 64;
        int bidL = v / (32 * 64);
        int kt = (v >> 6) % 32;
        int lane = v & 63;
        int n = lane & 15, quad = lane >> 4;
        int row = (n >> 2) * 512 + bidL * 4 + (n & 3);
        int k = kt * 32 + quad * 8;
        s = (k < 512) ? (Wih1 + (size_t)row * 512 + k) : (Whh1 + (size_t)row * 512 + (k - 512));
        d = wpk1 + (size_t)((bidL * 32 + kt) * 64 + lane) * 8;
    }
    #pragma unroll
    for (int i = 0; i < 8; ++i) d[i] = f2b_rne(s[i]);
}

// ---- the persistent tick loop ----
// CACHED=true: history mode (hmask large, virgin slots, cacheable h loads)
// CACHED=false: R4 mode (hmask=1 ping-pong, sc0sc1 bypass h loads)
template <int LAYER, bool CACHED>
__device__ void run_ticks(const float* __restrict__ x, const float* __restrict__ c0,
                          float* __restrict__ out, unsigned char* __restrict__ ws,
                          int bidL, u32 hmask, u64 h1off) {
    constexpr int NKT = (LAYER == 0) ? 24 : 32;
    u32* slots = (u32*)(ws + WS_BAR);
    u32* gen = (u32*)(ws + WS_GEN);
    const float* bs = (const float*)(ws + (LAYER == 0 ? WS_BSUM0 : WS_BSUM1));
    u16* h0base = (u16*)(ws + WS_H0);
    u16* h1base = (u16*)(ws + h1off);
    const u16* wpk = (const u16*)(ws + (LAYER == 0 ? WS_WPK0 : WS_WPK1));

    const int tid = threadIdx.x, lane = tid & 63, wave = tid >> 6;
    const int r16 = lane & 15, quad = lane >> 4, q8 = quad * 8;
    const int gg = r16 >> 2, jj = r16 & 3;
    const int b0 = wave * 16;
    const int col = bidL * 4 + jj;            // h column this lane finalizes
    const int myb = b0 + quad * 4 + gg;       // batch this lane finalizes
    const int sl0 = (quad << 4) | (0 << 2) | jj;
    const int sl1 = (quad << 4) | (1 << 2) | jj;
    const int sl2 = (quad << 4) | (2 << 2) | jj;
    const int sl3 = (quad << 4) | (3 << 2) | jj;

    // biases (hoisted), c state in register for the whole run
    const float bi = bs[0 * HH + col], bf_ = bs[1 * HH + col];
    const float bg = bs[2 * HH + col], bo = bs[3 * HH + col];
    float c = c0[myb * HH + col];

    // weight fragments (reloads, if any, hit L1/L2 — nothing invalidates)
    f32x4 wf[NKT];
    {
        const u16* wp = wpk + (size_t)(bidL * NKT * 64 + lane) * 8;
        #pragma unroll
        for (int kt = 0; kt < NKT; ++kt) wf[kt] = *(const f32x4*)(wp + (size_t)kt * 64 * 8);
        #pragma unroll
        for (int kt = 0; kt < NKT; ++kt) asm volatile("" : "+v"(wf[kt]));
    }

    // layer0: x prefetch registers (t=0 issued before the loop)
    float4 xf0[8], xf1[8];
    if (LAYER == 0) {
        const float* xp = x + (size_t)(b0 + r16) * CC + q8;
        #pragma unroll
        for (int kt = 0; kt < 8; ++kt) {
            xf0[kt] = *(const float4*)(xp + kt * 32);
            xf1[kt] = *(const float4*)(xp + kt * 32 + 4);
        }
    }

    for (int i = 0; i <= TT; ++i) {
        const bool active = (LAYER == 0) ? (i < TT) : (i >= 1);
        const int t = (LAYER == 0) ? i : i - 1;
        float h = 0.f;
        if (active) {
            f32x4 a0 = {0.f,0.f,0.f,0.f}, a1 = {0.f,0.f,0.f,0.f};
            f32x4 a2 = {0.f,0.f,0.f,0.f}, a3 = {0.f,0.f,0.f,0.f};
            if (LAYER == 0) {
                // 16 recurrent h fragments from slot t (one latency round)
                f32x4 afr[16];
                const u16* hp = h0base + (size_t)((u32)t & hmask) * S_ELEMS
                              + (size_t)(b0 + r16) * HH + q8;
                FragLd<0, 16, !CACHED>::go(afr, hp);
                #pragma unroll
                for (int kt = 0; kt < 8; ++kt) {      // x proj overlaps h-load flight
                    bf16x8 a = pack8(xf0[kt], xf1[kt]);
                    bf16x8 wv = __builtin_bit_cast(bf16x8, wf[kt]);
                    f32x4& dst = (kt & 2) ? ((kt & 1) ? a3 : a2) : ((kt & 1) ? a1 : a0);
                    dst = __builtin_amdgcn_mfma_f32_16x16x32_bf16(a, wv, dst, 0, 0, 0);
                }
                asm volatile("s_waitcnt vmcnt(0)" ::: "memory");
                __builtin_amdgcn_sched_barrier(0);
                #pragma unroll
                for (int kt = 0; kt < 16; ++kt) {
                    bf16x8 av = __builtin_bit_cast(bf16x8, afr[kt]);
                    bf16x8 wv = __builtin_bit_cast(bf16x8, wf[8 + kt]);
                    f32x4& dst = (kt & 2) ? ((kt & 1) ? a3 : a2) : ((kt & 1) ? a1 : a0);
                    dst = __builtin_amdgcn_mfma_f32_16x16x32_bf16(av, wv, dst, 0, 0, 0);
                }
            } else {
                // y0[t] = h0 slot t+1 (written by layer0 at its tick t);
                // h1 state = slot t (written at tick t-1)
                f32x4 afr[32];
                const u16* pa = h0base + (size_t)((u32)(t + 1) & hmask) * S_ELEMS
                              + (size_t)(b0 + r16) * HH + q8;
                const u16* pb = h1base + (size_t)((u32)t & hmask) * S_ELEMS
                              + (size_t)(b0 + r16) * HH + q8;
                FragLd<0, 16, !CACHED>::go(afr + 16, pb);   // h1 first
                FragLd<0, 16, !CACHED>::go(afr, pa);        // h0 second
                asm volatile("s_waitcnt vmcnt(16)" ::: "memory");  // h1 ready
                __builtin_amdgcn_sched_barrier(0);
                #pragma unroll
                for (int kt = 16; kt < 32; ++kt) {  // h1-MFMAs overlap h0 flight
                    bf16x8 av = __builtin_bit_cast(bf16x8, afr[kt]);
                    bf16x8 wv = __builtin_bit_cast(bf16x8, wf[kt]);
                    f32x4& dst = (kt & 2) ? ((kt & 1) ? a3 : a2) : ((kt & 1) ? a1 : a0);
                    dst = __builtin_amdgcn_mfma_f32_16x16x32_bf16(av, wv, dst, 0, 0, 0);
                }
                asm volatile("s_waitcnt vmcnt(0)" ::: "memory");
                __builtin_amdgcn_sched_barrier(0);
                #pragma unroll
                for (int kt = 0; kt < 16; ++kt) {
                    bf16x8 av = __builtin_bit_cast(bf16x8, afr[kt]);
                    bf16x8 wv = __builtin_bit_cast(bf16x8, wf[kt]);
                    f32x4& dst = (kt & 2) ? ((kt & 1) ? a3 : a2) : ((kt & 1) ? a1 : a0);
                    dst = __builtin_amdgcn_mfma_f32_16x16x32_bf16(av, wv, dst, 0, 0, 0);
                }
            }
            f32x4 acc = (a0 + a1) + (a2 + a3);

            // gates for (myb, col): lanes sharing (quad,jj), gg = gate
            float gi = 0.f, gf = 0.f, gc = 0.f, go = 0.f;
            #pragma unroll
            for (int r = 0; r < 4; ++r) {
                float v0 = __shfl(acc[r], sl0, 64);
                float v1 = __shfl(acc[r], sl1, 64);
                float v2 = __shfl(acc[r], sl2, 64);
                float v3 = __shfl(acc[r], sl3, 64);
                if (r == gg) { gi = v0; gf = v1; gc = v2; go = v3; }
            }
            gi = sigf(gi + bi);
            gf = sigf(gf + bf_);
            gc = tanh_f(gc + bg);
            go = sigf(go + bo);
            c = gf * c + gi * gc;
            h = go * tanh_f(c);

            // h store: slot t+1, write-through to LLC (the only pre-flag store)
            u16* hw = (LAYER == 0) ? (h0base + (size_t)((u32)(t + 1) & hmask) * S_ELEMS)
                                   : (h1base + (size_t)((u32)(t + 1) & hmask) * S_ELEMS);
            st_h_sc(&hw[myb * HH + col], f2b_rne(h));
        }
        // ---- barrier arrival: drain h store, then raise flag ----
        if (i < TT) {
            asm volatile("s_waitcnt vmcnt(0)" ::: "memory");
            __syncthreads();   // all waves of this block drained
            if (tid == 0)
                st_u32_sc(&slots[(u32)blockIdx.x * 32], (u32)(i + 1));
        }
        // ---- shadow work while flags propagate / peers finish ----
        if (active) {
            if (LAYER == 1) out[(size_t)t * S_ELEMS + myb * HH + col] = h;
            if (t == TT - 1) {
                float* fin = out + Y_ELEMS + (LAYER == 0 ? 0 : 2) * S_ELEMS;
                fin[myb * HH + col] = h;
                fin[S_ELEMS + myb * HH + col] = c;
            }
        }
        if (LAYER == 0 && i + 1 < TT) {      // prefetch x[t+1] into registers
            const float* xp = x + ((size_t)(i + 1) * BB + b0 + r16) * CC + q8;
            #pragma unroll
            for (int kt = 0; kt < 8; ++kt) {
                xf0[kt] = *(const float4*)(xp + kt * 32);
                xf1[kt] = *(const float4*)(xp + kt * 32 + 4);
            }
        }
        // ---- barrier completion: aggregator (block 0) or gen-poll (others) ----
        if (i < TT) {
            const u32 tgt = (u32)(i + 1);
            if (blockIdx.x == 0) {
                if (tid < 64) {  // wave 0 scans all 256 slots, 4 per lane
                    const u32* p0 = slots + ((u32)tid * 4 + 0) * 32;
                    const u32* p1 = slots + ((u32)tid * 4 + 1) * 32;
                    const u32* p2 = slots + ((u32)tid * 4 + 2) * 32;
                    const u32* p3 = slots + ((u32)tid * 4 + 3) * 32;
                    u32 m;
                    do {
                        u32 va = ld_u32_sc(p0);
                        u32 vb = ld_u32_sc(p1);
                        u32 vc = ld_u32_sc(p2);
                        u32 vd = ld_u32_sc(p3);
                        m = min(min(va, vb), min(vc, vd));
                    } while (m < tgt);
                }
                __syncthreads();
                if (tid == 0) {
                    #pragma unroll
                    for (int k2 = 0; k2 < 4; ++k2) st_u32_sc(gen + k2 * 32, tgt);
                }
            } else {
                if (tid == 0) {
                    const u32* gp = gen + ((u32)blockIdx.x & 3) * 32;
                    while (ld_u32_sc(gp) < tgt) { }
                }
                __syncthreads();
            }
        }
    }
}

template <bool CACHED>
__global__ __launch_bounds__(256) __attribute__((amdgpu_waves_per_eu(1, 1)))
void k_lstm(const float* __restrict__ x,
            const float* __restrict__ c00,
            const float* __restrict__ c01,
            float* __restrict__ out,
            unsigned char* __restrict__ ws, u32 hmask, u64 h1off) {
    const int bid = blockIdx.x;
    if (bid < 128) run_ticks<0, CACHED>(x, c00, out, ws, bid, hmask, h1off);
    else           run_ticks<1, CACHED>(x, c01, out, ws, bid - 128, hmask, h1off);
}

extern "C" void kernel_launch(void* const* d_in, const int* in_sizes, int n_in,
                              void* d_out, int out_size, void* d_ws, size_t ws_size,
                              hipStream_t stream) {
    const float* x    = (const float*)d_in[0];
    const float* h0_0 = (const float*)d_in[1];
    const float* c0_0 = (const float*)d_in[2];
    const float* h0_1 = (const float*)d_in[3];
    const float* c0_1 = (const float*)d_in[4];
    const float* Wih0 = (const float*)d_in[5];
    const float* Whh0 = (const float*)d_in[6];
    const float* bih0 = (const float*)d_in[7];
    const float* bhh0 = (const float*)d_in[8];
    const float* Wih1 = (const float*)d_in[9];
    const float* Whh1 = (const float*)d_in[10];
    const float* bih1 = (const float*)d_in[11];
    const float* bhh1 = (const float*)d_in[12];
    float* out = (float*)d_out;
    unsigned char* ws = (unsigned char*)d_ws;

    // history mode needs 1025 slots per layer (no address reuse)
    const u64 HIST_NEED = (u64)WS_H0 + 2ull * 1025ull * H_SLOT_BYTES;  // 141,742,080
    const bool big = (u64)ws_size >= HIST_NEED;
    const u32 hmask = big ? 4095u : 1u;                 // no-op mask in history mode
    const u64 nsl = big ? 1025ull : 2ull;
    const u64 h1off = (u64)WS_H0 + nsl * H_SLOT_BYTES;  // byte offset of h1 base

    k_init<<<128, 256, 0, stream>>>(bih0, bhh0, bih1, bhh1, h0_0, h0_1, ws, h1off);
    k_wprep<<<1792, 256, 0, stream>>>(Wih0, Whh0, Wih1, Whh1, ws);
    if (big) k_lstm<true><<<256, 256, 0, stream>>>(x, c0_0, c0_1, out, ws, hmask, h1off);
    else     k_lstm<false><<<256, 256, 0, stream>>>(x, c0_0, c0_1, out, ws, hmask, h1off);
}